// Round 1
// baseline (10871.578 us; speedup 1.0000x reference)
//
#include <hip/hip_runtime.h>
#include <hip/hip_cooperative_groups.h>
#include <math.h>

namespace cg = cooperative_groups;

// Problem dims (fixed by reference)
#define BB 32
#define CC 8
#define TT 64
#define FF 256
#define HH 512
#define G3 1536
#define NSEQ 256            // BB*CC
#define MROWS 16384         // NSEQ*TT

// ---------------- input GEMM: C[M][N] = A[M][K] @ W[N][K]^T + bias[N] ----------------
#define TMg 128
#define TNg 128
#define TKg 16

__global__ __launch_bounds__(256) void gemm_bias(
    const float* __restrict__ A, const float* __restrict__ W,
    const float* __restrict__ bias, float* __restrict__ C,
    int M, int N, int K)
{
  __shared__ float As[TKg][TMg + 4];   // [k][m], padded
  __shared__ float Ws[TKg][TNg + 4];   // [k][n], padded
  const int bm = blockIdx.y * TMg;
  const int bn = blockIdx.x * TNg;
  const int tid = threadIdx.x;
  const int tx = tid & 15;   // n dim
  const int ty = tid >> 4;   // m dim
  float acc[8][8];
#pragma unroll
  for (int i = 0; i < 8; ++i)
#pragma unroll
    for (int j = 0; j < 8; ++j) acc[i][j] = 0.f;

  for (int k0 = 0; k0 < K; k0 += TKg) {
    __syncthreads();
#pragma unroll
    for (int i = 0; i < 8; ++i) {
      int e = i * 256 + tid;
      int r = e >> 4;          // tile row (m or n), 0..127
      int c = e & 15;          // k within tile
      As[c][r] = A[(size_t)(bm + r) * K + (k0 + c)];
      Ws[c][r] = W[(size_t)(bn + r) * K + (k0 + c)];
    }
    __syncthreads();
#pragma unroll
    for (int k = 0; k < TKg; ++k) {
      float a[8], w[8];
#pragma unroll
      for (int i = 0; i < 8; ++i) a[i] = As[k][ty * 8 + i];
#pragma unroll
      for (int j = 0; j < 8; ++j) w[j] = Ws[k][tx + 16 * j];
#pragma unroll
      for (int i = 0; i < 8; ++i)
#pragma unroll
        for (int j = 0; j < 8; ++j) acc[i][j] = fmaf(a[i], w[j], acc[i][j]);
    }
  }
#pragma unroll
  for (int i = 0; i < 8; ++i) {
    size_t m = (size_t)(bm + ty * 8 + i);
#pragma unroll
    for (int j = 0; j < 8; ++j) {
      int n = bn + tx + 16 * j;
      C[m * N + n] = acc[i][j] + bias[n];
    }
  }
}

// ---------------- recurrent scan (one layer), cooperative launch ----------------
// 256 blocks = 64 col-groups (8 h-cols each) x 4 seq-groups (64 seqs each).
// Block keeps its Whh slice (24 rows x 512) resident in LDS for all 64 steps.
// h double-buffered in global; one grid.sync per step.
#define SCG 64
#define JPB 8      // h-cols per block
#define SPB 64     // seqs per block
#define KC 32      // k staging chunk
#define STH 128    // threads

__global__ __launch_bounds__(STH) void gru_scan(
    const float* __restrict__ gi,    // [NSEQ][TT][G3] precomputed x@Wih^T + bih
    const float* __restrict__ Whh,   // [G3][HH]
    const float* __restrict__ bhh,   // [G3]
    float* __restrict__ hbuf,        // [2][NSEQ][HH]
    float* __restrict__ yout)        // [NSEQ][TT][HH] or nullptr
{
  cg::grid_group grid = cg::this_grid();
  __shared__ float whs[3 * JPB][HH + 4];        // 24 x 516 fp32 = 49536 B
  __shared__ float hs4[SPB / 4][KC + 1][4];     // 16 x 33 x 4 fp32 = 8448 B

  const int bid = blockIdx.x;
  const int cgi = bid & (SCG - 1);
  const int sgi = bid >> 6;
  const int col0 = cgi * JPB;
  const int seq0 = sgi * SPB;
  const int tid = threadIdx.x;
  const int si = tid & 15;    // seq quad: seqs seq0 + 4*si .. +3
  const int jj = tid >> 4;    // 0..7: this thread's h-column (col0+jj)

  // Load Whh slice once: row l (l = g*8 + jl) <- global row g*512 + col0 + jl
  for (int e4 = tid; e4 < 3 * JPB * (HH / 4); e4 += STH) {
    int l = e4 >> 7;          // / (HH/4)
    int k4 = e4 & 127;
    int grow = (l >> 3) * HH + col0 + (l & 7);
    float4 v = *reinterpret_cast<const float4*>(&Whh[(size_t)grow * HH + k4 * 4]);
    *reinterpret_cast<float4*>(&whs[l][k4 * 4]) = v;
  }

  float bh[3];
#pragma unroll
  for (int g = 0; g < 3; ++g) bh[g] = bhh[g * HH + col0 + jj];

  // persistent h for this thread's 4 (seq, col) cells; also zero-init global h buf0
  float hreg[4] = {0.f, 0.f, 0.f, 0.f};
#pragma unroll
  for (int s = 0; s < 4; ++s)
    hbuf[(size_t)(seq0 + si * 4 + s) * HH + col0 + jj] = 0.f;

  __threadfence();
  grid.sync();
  __threadfence();

  for (int t = 0; t < TT; ++t) {
    const float* __restrict__ hprev = hbuf + (size_t)(t & 1) * NSEQ * HH;
    float* __restrict__ hcur = hbuf + (size_t)((t + 1) & 1) * NSEQ * HH;

    float acc[4][3];
#pragma unroll
    for (int s = 0; s < 4; ++s)
#pragma unroll
      for (int g = 0; g < 3; ++g) acc[s][g] = bh[g];

    for (int k0 = 0; k0 < HH; k0 += KC) {
      __syncthreads();
      // stage h[seq0..+64][k0..+KC] into seq-interleaved LDS: hs4[si][k][s]
#pragma unroll
      for (int i = 0; i < (SPB * KC) / STH; ++i) {   // 16 elems/thread
        int e = i * STH + tid;
        int k = e & (KC - 1);
        int s64 = e >> 5;
        hs4[s64 >> 2][k][s64 & 3] = hprev[(size_t)(seq0 + s64) * HH + (k0 + k)];
      }
      __syncthreads();
#pragma unroll 2
      for (int k = 0; k < KC; k += 4) {
        float wv[3][4];
#pragma unroll
        for (int g = 0; g < 3; ++g) {
          float4 w = *reinterpret_cast<const float4*>(&whs[g * JPB + jj][k0 + k]);
          wv[g][0] = w.x; wv[g][1] = w.y; wv[g][2] = w.z; wv[g][3] = w.w;
        }
#pragma unroll
        for (int q = 0; q < 4; ++q) {
          float4 hv = *reinterpret_cast<const float4*>(&hs4[si][k + q][0]);
          float hq[4] = {hv.x, hv.y, hv.z, hv.w};
#pragma unroll
          for (int g = 0; g < 3; ++g)
#pragma unroll
            for (int s = 0; s < 4; ++s)
              acc[s][g] = fmaf(hq[s], wv[g][q], acc[s][g]);
        }
      }
    }

    // gates + h update for 4 seqs at column col0+jj
#pragma unroll
    for (int s = 0; s < 4; ++s) {
      int n = seq0 + si * 4 + s;
      size_t grow = ((size_t)n * TT + t) * G3;
      float ir  = gi[grow + col0 + jj];
      float iz  = gi[grow + HH + col0 + jj];
      float inn = gi[grow + 2 * HH + col0 + jj];
      float r = 1.f / (1.f + expf(-(ir + acc[s][0])));
      float z = 1.f / (1.f + expf(-(iz + acc[s][1])));
      float nn = tanhf(inn + r * acc[s][2]);
      float hnew = (1.f - z) * nn + z * hreg[s];
      hreg[s] = hnew;
      hcur[(size_t)n * HH + col0 + jj] = hnew;
      if (yout) yout[((size_t)n * TT + t) * HH + col0 + jj] = hnew;
    }
    __threadfence();
    grid.sync();
    __threadfence();
  }
}

// ---------------- final FC + channel mean ----------------
__global__ __launch_bounds__(256) void fc_mean(
    const float* __restrict__ hfin,  // [NSEQ][HH] (hbuf buffer 0)
    const float* __restrict__ fcW,   // [HH] (O=1)
    const float* __restrict__ fcb,   // [1]
    float* __restrict__ out)         // [BB]
{
  __shared__ float red[256];
  const int b = blockIdx.x;
  const int tid = threadIdx.x;
  float sum = 0.f;
  for (int e = tid; e < CC * HH; e += 256) {
    int c = e >> 9;
    int k = e & (HH - 1);
    sum += hfin[(size_t)(b * CC + c) * HH + k] * fcW[k];
  }
  red[tid] = sum;
  __syncthreads();
  for (int w = 128; w > 0; w >>= 1) {
    if (tid < w) red[tid] += red[tid + w];
    __syncthreads();
  }
  if (tid == 0) out[b] = red[0] * (1.f / CC) + fcb[0];
}

extern "C" void kernel_launch(void* const* d_in, const int* in_sizes, int n_in,
                              void* d_out, int out_size, void* d_ws, size_t ws_size,
                              hipStream_t stream)
{
  const float* x    = (const float*)d_in[0];
  const float* Wih0 = (const float*)d_in[1];
  const float* Whh0 = (const float*)d_in[2];
  const float* bih0 = (const float*)d_in[3];
  const float* bhh0 = (const float*)d_in[4];
  const float* Wih1 = (const float*)d_in[5];
  const float* Whh1 = (const float*)d_in[6];
  const float* bih1 = (const float*)d_in[7];
  const float* bhh1 = (const float*)d_in[8];
  const float* fcW  = (const float*)d_in[9];
  const float* fcb  = (const float*)d_in[10];
  float* out = (float*)d_out;

  // workspace layout: gi (100.7 MB) | y0 (33.6 MB) | hbuf (1 MB)  -> ~135.3 MB
  char* ws = (char*)d_ws;
  float* gibuf = (float*)ws;                                              // [MROWS][G3]
  float* y0    = (float*)(ws + (size_t)MROWS * G3 * 4);                   // [MROWS][HH]
  float* hbuf  = (float*)(ws + (size_t)MROWS * G3 * 4 + (size_t)MROWS * HH * 4); // [2][NSEQ][HH]

  // layer 0: gi0 = x @ Wih0^T + bih0   (K = FF = 256)
  gemm_bias<<<dim3(G3 / TNg, MROWS / TMg), 256, 0, stream>>>(x, Wih0, bih0, gibuf, MROWS, G3, FF);

  // layer 0 scan (writes y0, leaves final h unused)
  {
    const float* giarg = gibuf;
    const float* wharg = Whh0;
    const float* bharg = bhh0;
    float* hbarg = hbuf;
    float* yarg  = y0;
    void* args[] = {(void*)&giarg, (void*)&wharg, (void*)&bharg, (void*)&hbarg, (void*)&yarg};
    hipLaunchCooperativeKernel((const void*)gru_scan, dim3(NSEQ), dim3(STH), args, 0, stream);
  }

  // layer 1: gi1 = y0 @ Wih1^T + bih1  (K = HH = 512), reuse gi buffer
  gemm_bias<<<dim3(G3 / TNg, MROWS / TMg), 256, 0, stream>>>(y0, Wih1, bih1, gibuf, MROWS, G3, HH);

  // layer 1 scan (no y output; final h lands in hbuf[0] since TT is even)
  {
    const float* giarg = gibuf;
    const float* wharg = Whh1;
    const float* bharg = bhh1;
    float* hbarg = hbuf;
    float* yarg  = nullptr;
    void* args[] = {(void*)&giarg, (void*)&wharg, (void*)&bharg, (void*)&hbarg, (void*)&yarg};
    hipLaunchCooperativeKernel((const void*)gru_scan, dim3(NSEQ), dim3(STH), args, 0, stream);
  }

  // FC + mean over channels
  fc_mean<<<dim3(BB), 256, 0, stream>>>(hbuf, fcW, fcb, out);
}

// Round 2
// 5029.786 us; speedup vs baseline: 2.1614x; 2.1614x over previous
//
#include <hip/hip_runtime.h>
#include <math.h>

// Problem dims (fixed by reference)
#define BB 32
#define CC 8
#define TT 64
#define FF 256
#define HH 512
#define G3 1536
#define NSEQ 256            // BB*CC
#define MROWS 16384         // NSEQ*TT

// ---------------- input GEMM: C[M][N] = A[M][K] @ W[N][K]^T + bias[N] ----------------
#define TMg 128
#define TNg 128
#define TKg 16

__global__ __launch_bounds__(256) void gemm_bias(
    const float* __restrict__ A, const float* __restrict__ W,
    const float* __restrict__ bias, float* __restrict__ C,
    int M, int N, int K)
{
  __shared__ float As[TKg][TMg + 4];   // [k][m], padded
  __shared__ float Ws[TKg][TNg + 4];   // [k][n], padded
  const int bm = blockIdx.y * TMg;
  const int bn = blockIdx.x * TNg;
  const int tid = threadIdx.x;
  const int tx = tid & 15;   // n dim
  const int ty = tid >> 4;   // m dim
  float acc[8][8];
#pragma unroll
  for (int i = 0; i < 8; ++i)
#pragma unroll
    for (int j = 0; j < 8; ++j) acc[i][j] = 0.f;

  for (int k0 = 0; k0 < K; k0 += TKg) {
    __syncthreads();
#pragma unroll
    for (int i = 0; i < 8; ++i) {
      int e = i * 256 + tid;
      int r = e >> 4;          // tile row (m or n), 0..127
      int c = e & 15;          // k within tile
      As[c][r] = A[(size_t)(bm + r) * K + (k0 + c)];
      Ws[c][r] = W[(size_t)(bn + r) * K + (k0 + c)];
    }
    __syncthreads();
#pragma unroll
    for (int k = 0; k < TKg; ++k) {
      float a[8], w[8];
#pragma unroll
      for (int i = 0; i < 8; ++i) a[i] = As[k][ty * 8 + i];
#pragma unroll
      for (int j = 0; j < 8; ++j) w[j] = Ws[k][tx + 16 * j];
#pragma unroll
      for (int i = 0; i < 8; ++i)
#pragma unroll
        for (int j = 0; j < 8; ++j) acc[i][j] = fmaf(a[i], w[j], acc[i][j]);
    }
  }
#pragma unroll
  for (int i = 0; i < 8; ++i) {
    size_t m = (size_t)(bm + ty * 8 + i);
#pragma unroll
    for (int j = 0; j < 8; ++j) {
      int n = bn + tx + 16 * j;
      C[m * N + n] = acc[i][j] + bias[n];
    }
  }
}

// ---------------- weight transpose: W[G3][HH] -> WT[HH][G3] ----------------
__global__ __launch_bounds__(256) void transpose_w(
    const float* __restrict__ W, float* __restrict__ WT)
{
  __shared__ float tile[32][33];
  const int bx = blockIdx.x;           // along HH (k), 512/32 = 16
  const int by = blockIdx.y;           // along G3 (rows), 1536/32 = 48
  const int tx = threadIdx.x & 31;
  const int ty = threadIdx.x >> 5;     // 0..7
#pragma unroll
  for (int i = 0; i < 32; i += 8)
    tile[ty + i][tx] = W[(size_t)(by * 32 + ty + i) * HH + bx * 32 + tx];
  __syncthreads();
#pragma unroll
  for (int i = 0; i < 32; i += 8)
    WT[(size_t)(bx * 32 + ty + i) * G3 + by * 32 + tx] = tile[tx][ty + i];
}

// ---------------- recurrent scan: block-local, NO cross-block sync ----------------
// 64 blocks x 4 seqs x 512 threads. Thread j owns h-column j (all 3 gates, all
// 4 seqs). h[4][512] lives in LDS; weights stream from L2 each step.
// TRANS=true: W is WT[HH][G3] (coalesced scalar loads).
// TRANS=false: W is Whh[G3][HH] (per-thread row streaming, float4).
#define QS 4
#define SCTH 512

template<bool TRANS>
__global__ __launch_bounds__(SCTH) void gru_scan2(
    const float* __restrict__ gi,    // [NSEQ][TT][G3]
    const float* __restrict__ W,     // see above
    const float* __restrict__ bhh,   // [G3]
    float* __restrict__ hfin,        // [NSEQ][HH]
    float* __restrict__ yout)        // [NSEQ][TT][HH] or nullptr
{
  __shared__ __align__(16) float hs[HH][QS];   // 8 KB
  const int col = threadIdx.x;
  const int seq0 = blockIdx.x * QS;

  const float bh0 = bhh[col];
  const float bh1 = bhh[HH + col];
  const float bh2 = bhh[2 * HH + col];

  const float* w0p = nullptr; const float* w1p = nullptr; const float* w2p = nullptr;
  if (!TRANS) {
    w0p = W + (size_t)col * HH;
    w1p = W + (size_t)(HH + col) * HH;
    w2p = W + (size_t)(2 * HH + col) * HH;
  }

  *reinterpret_cast<float4*>(&hs[col][0]) = make_float4(0.f, 0.f, 0.f, 0.f);
  __syncthreads();

  for (int t = 0; t < TT; ++t) {
    float acc0[QS], acc1[QS], acc2[QS];
#pragma unroll
    for (int s = 0; s < QS; ++s) { acc0[s] = bh0; acc1[s] = bh1; acc2[s] = bh2; }

    float4 ho = *reinterpret_cast<const float4*>(&hs[col][0]);
    float hold[QS] = {ho.x, ho.y, ho.z, ho.w};

#pragma unroll 2
    for (int k0 = 0; k0 < HH; k0 += 4) {
      float w[3][4];
      if (TRANS) {
#pragma unroll
        for (int kk = 0; kk < 4; ++kk) {
          size_t base = (size_t)(k0 + kk) * G3 + col;
          w[0][kk] = W[base];
          w[1][kk] = W[base + HH];
          w[2][kk] = W[base + 2 * HH];
        }
      } else {
        float4 a = *reinterpret_cast<const float4*>(&w0p[k0]);
        w[0][0] = a.x; w[0][1] = a.y; w[0][2] = a.z; w[0][3] = a.w;
        float4 b = *reinterpret_cast<const float4*>(&w1p[k0]);
        w[1][0] = b.x; w[1][1] = b.y; w[1][2] = b.z; w[1][3] = b.w;
        float4 c = *reinterpret_cast<const float4*>(&w2p[k0]);
        w[2][0] = c.x; w[2][1] = c.y; w[2][2] = c.z; w[2][3] = c.w;
      }
#pragma unroll
      for (int kk = 0; kk < 4; ++kk) {
        float4 h4 = *reinterpret_cast<const float4*>(&hs[k0 + kk][0]);  // broadcast
        float hq[4] = {h4.x, h4.y, h4.z, h4.w};
#pragma unroll
        for (int s = 0; s < QS; ++s) {
          acc0[s] = fmaf(hq[s], w[0][kk], acc0[s]);
          acc1[s] = fmaf(hq[s], w[1][kk], acc1[s]);
          acc2[s] = fmaf(hq[s], w[2][kk], acc2[s]);
        }
      }
    }

    __syncthreads();   // all reads of hs for this step complete

    float hnew[QS];
#pragma unroll
    for (int s = 0; s < QS; ++s) {
      size_t grow = ((size_t)(seq0 + s) * TT + t) * G3;
      float ir  = gi[grow + col];
      float iz  = gi[grow + HH + col];
      float inn = gi[grow + 2 * HH + col];
      float r = 1.f / (1.f + expf(-(ir + acc0[s])));
      float z = 1.f / (1.f + expf(-(iz + acc1[s])));
      float nn = tanhf(inn + r * acc2[s]);
      hnew[s] = (1.f - z) * nn + z * hold[s];
      if (yout) yout[((size_t)(seq0 + s) * TT + t) * HH + col] = hnew[s];
    }
    *reinterpret_cast<float4*>(&hs[col][0]) =
        make_float4(hnew[0], hnew[1], hnew[2], hnew[3]);
    __syncthreads();   // hs updated for next step
  }

#pragma unroll
  for (int s = 0; s < QS; ++s)
    hfin[(size_t)(seq0 + s) * HH + col] = hs[col][s];
}

// ---------------- final FC + channel mean ----------------
__global__ __launch_bounds__(256) void fc_mean(
    const float* __restrict__ hfin,  // [NSEQ][HH]
    const float* __restrict__ fcW,   // [HH] (O=1)
    const float* __restrict__ fcb,   // [1]
    float* __restrict__ out)         // [BB]
{
  __shared__ float red[256];
  const int b = blockIdx.x;
  const int tid = threadIdx.x;
  float sum = 0.f;
  for (int e = tid; e < CC * HH; e += 256) {
    int c = e >> 9;
    int k = e & (HH - 1);
    sum += hfin[(size_t)(b * CC + c) * HH + k] * fcW[k];
  }
  red[tid] = sum;
  __syncthreads();
  for (int w = 128; w > 0; w >>= 1) {
    if (tid < w) red[tid] += red[tid + w];
    __syncthreads();
  }
  if (tid == 0) out[b] = red[0] * (1.f / CC) + fcb[0];
}

extern "C" void kernel_launch(void* const* d_in, const int* in_sizes, int n_in,
                              void* d_out, int out_size, void* d_ws, size_t ws_size,
                              hipStream_t stream)
{
  const float* x    = (const float*)d_in[0];
  const float* Wih0 = (const float*)d_in[1];
  const float* Whh0 = (const float*)d_in[2];
  const float* bih0 = (const float*)d_in[3];
  const float* bhh0 = (const float*)d_in[4];
  const float* Wih1 = (const float*)d_in[5];
  const float* Whh1 = (const float*)d_in[6];
  const float* bih1 = (const float*)d_in[7];
  const float* bhh1 = (const float*)d_in[8];
  const float* fcW  = (const float*)d_in[9];
  const float* fcb  = (const float*)d_in[10];
  float* out = (float*)d_out;

  // ws layout (mandatory part = 134.74 MB, proven to fit in round 0):
  //   gi   [MROWS][G3]   100,663,296 B @ 0
  //   y0   [MROWS][HH]    33,554,432 B @ 100,663,296   (dead after GEMM1; WT1 aliases it)
  //   hfin [NSEQ][HH]        524,288 B @ 134,217,728
  //   WT0  [HH][G3]        3,145,728 B @ 134,742,016   (optional, if ws_size allows)
  char* ws = (char*)d_ws;
  float* gibuf = (float*)ws;
  float* y0    = (float*)(ws + 100663296ull);
  float* hfin  = (float*)(ws + 134217728ull);
  float* wt0   = (float*)(ws + 134742016ull);
  float* wt1   = (float*)(ws + 100663296ull);   // aliases y0 (used only after GEMM1)
  const bool trans0 = (ws_size >= 134742016ull + 3145728ull);

  // layer 0 input GEMM: gi = x @ Wih0^T + bih0   (K = FF)
  gemm_bias<<<dim3(G3 / TNg, MROWS / TMg), 256, 0, stream>>>(x, Wih0, bih0, gibuf, MROWS, G3, FF);

  // layer 0 scan
  if (trans0) {
    transpose_w<<<dim3(16, 48), 256, 0, stream>>>(Whh0, wt0);
    gru_scan2<true><<<dim3(NSEQ / QS), SCTH, 0, stream>>>(gibuf, wt0, bhh0, hfin, y0);
  } else {
    gru_scan2<false><<<dim3(NSEQ / QS), SCTH, 0, stream>>>(gibuf, Whh0, bhh0, hfin, y0);
  }

  // layer 1 input GEMM: gi = y0 @ Wih1^T + bih1  (K = HH)
  gemm_bias<<<dim3(G3 / TNg, MROWS / TMg), 256, 0, stream>>>(y0, Wih1, bih1, gibuf, MROWS, G3, HH);

  // layer 1 scan (y0 now dead -> WT1 in its space)
  transpose_w<<<dim3(16, 48), 256, 0, stream>>>(Whh1, wt1);
  gru_scan2<true><<<dim3(NSEQ / QS), SCTH, 0, stream>>>(gibuf, wt1, bhh1, hfin, nullptr);

  // FC + channel mean
  fc_mean<<<dim3(BB), 256, 0, stream>>>(hfin, fcW, fcb, out);
}